// Round 7
// baseline (719.848 us; speedup 1.0000x reference)
//
#include <hip/hip_runtime.h>
#include <hip/hip_bf16.h>
#include <math.h>

#define NN 50000
#define NE 800000
#define NGRAPH 128
#define HEADS 8
#define CH 32
#define HID 256
#define NEG_SLOPE 0.2f

typedef __attribute__((ext_vector_type(8))) short short8;
typedef __attribute__((ext_vector_type(4))) short short4v;
typedef __attribute__((ext_vector_type(4))) float v4f;

__device__ inline float bflo(unsigned u) { return __builtin_bit_cast(float, u << 16); }
__device__ inline float bfhi(unsigned u) { return __builtin_bit_cast(float, u & 0xFFFF0000u); }
__device__ inline float bf2f(short s) {
    return __builtin_bit_cast(float, ((unsigned)(unsigned short)s) << 16);
}
__device__ inline short f2bf(float f) {
    __hip_bfloat16 b = __float2bfloat16(f);
    return __builtin_bit_cast(short, b);
}
// monotonic float<->uint order-preserving map (for atomicMax on floats)
__device__ inline unsigned fkey(float f) {
    unsigned u = __builtin_bit_cast(unsigned, f);
    return (u & 0x80000000u) ? ~u : (u | 0x80000000u);
}
__device__ inline float unfkey(unsigned u) {
    unsigned v = (u & 0x80000000u) ? (u & 0x7FFFFFFFu) : ~u;
    return __builtin_bit_cast(float, v);
}

// ---------------- CSR build ----------------

__global__ void init_counts_kernel(int* counts, int n) {
    int i = blockIdx.x * blockDim.x + threadIdx.x;
    if (i < n) counts[i] = 1;  // self-loop
}

__global__ void count_edges_kernel(const int* __restrict__ dst, int* counts, int e) {
    int i = blockIdx.x * blockDim.x + threadIdx.x;
    if (i < e) atomicAdd(&counts[dst[i]], 1);
}

__device__ inline int wave_incl_scan(int v, int lane) {
#pragma unroll
    for (int off = 1; off < 64; off <<= 1) {
        int u = __shfl_up(v, off);
        if (lane >= off) v += u;
    }
    return v;
}

__global__ __launch_bounds__(1024) void scan_part_kernel(const int* __restrict__ counts,
                                                         int* partial, int n) {
    int i = blockIdx.x * 1024 + threadIdx.x;
    int v = (i < n) ? counts[i] : 0;
    int lane = threadIdx.x & 63, w = threadIdx.x >> 6;
    __shared__ int ws[16];
    int sv = wave_incl_scan(v, lane);
    if (lane == 63) ws[w] = sv;
    __syncthreads();
    if (threadIdx.x == 0) {
        int tot = 0;
#pragma unroll
        for (int j = 0; j < 16; j++) tot += ws[j];
        partial[blockIdx.x] = tot;
    }
}

__global__ void scan_offsets_kernel(const int* __restrict__ partial, int* blockOff, int nb) {
    int lane = threadIdx.x;
    int v = (lane < nb) ? partial[lane] : 0;
    int incl = wave_incl_scan(v, lane);
    if (lane < nb) blockOff[lane] = incl - v;
}

__global__ __launch_bounds__(1024) void scan_final_kernel(const int* __restrict__ counts,
                                                          const int* __restrict__ blockOff,
                                                          int* row_ptr, int* cursor, int n) {
    int i = blockIdx.x * 1024 + threadIdx.x;
    int v = (i < n) ? counts[i] : 0;
    int lane = threadIdx.x & 63, w = threadIdx.x >> 6;
    __shared__ int ws[17];
    int sv = wave_incl_scan(v, lane);
    if (lane == 63) ws[w] = sv;
    __syncthreads();
    if (w == 0) {
        int t = (lane < 16) ? ws[lane] : 0;
        int ts = wave_incl_scan(t, lane);
        if (lane < 16) ws[lane] = ts;
    }
    __syncthreads();
    int waveBase = (w > 0) ? ws[w - 1] : 0;
    int off = blockOff[blockIdx.x];
    int incl = waveBase + sv;
    if (i < n) {
        int ex = off + incl - v;
        row_ptr[i] = ex;
        cursor[i] = ex;
        if (i == n - 1) row_ptr[n] = off + incl;
    }
}

__global__ void scatter_kernel(const int* __restrict__ ei, int* cursor, int* srcs, int ne, int nn) {
    int i = blockIdx.x * blockDim.x + threadIdx.x;
    if (i < ne) {
        int s = ei[i];
        int d = ei[ne + i];
        int pos = atomicAdd(&cursor[d], 1);
        srcs[pos] = s;
    } else if (i < ne + nn) {
        int v = i - ne;
        int pos = atomicAdd(&cursor[v], 1);
        srcs[pos] = v;
    }
}

// ---------------- conversions ----------------

__global__ void xcvt_kernel(const float* __restrict__ x, short* __restrict__ xb, int n4) {
    int i = blockIdx.x * blockDim.x + threadIdx.x;
    if (i >= n4) return;
    float4 v = ((const float4*)x)[i];
    union { short4v s; __hip_bfloat162 b[2]; } p;
    p.b[0] = __float22bfloat162_rn(make_float2(v.x, v.y));
    p.b[1] = __float22bfloat162_rn(make_float2(v.z, v.w));
    ((short4v*)xb)[i] = p.s;
}

// W[K,256] f32 -> Wt[256,K] bf16
__global__ void wcvt_kernel(const float* __restrict__ W, short* __restrict__ Wt, int K) {
    int n = blockIdx.x;
    for (int k = threadIdx.x; k < K; k += blockDim.x)
        Wt[(size_t)n * K + k] = f2bf(W[(size_t)k * 256 + n]);
}

// ---------------- MFMA GEMM + fused alpha/gmax epilogue ----------------
// H[M,256](bf16) = A[M,K](bf16) @ Wt^T; alS/alD[node,head] dots; per-head global max.
// block = 64 rows x 256 cols, 4 waves; wave (wm,wn) = rows wm*32..+32, cols wn*128..+128.
// A staged whole-K in LDS (coalesced, +8 pad); epilogue tile unions with A stage.

template <int K>
__global__ __launch_bounds__(256) void gemm_alpha_kernel(const short* __restrict__ A,
                                                         const short* __restrict__ Wt,
                                                         const float* __restrict__ a_src,
                                                         const float* __restrict__ a_dst,
                                                         short* __restrict__ H,
                                                         float* __restrict__ alS,
                                                         float* __restrict__ alD,
                                                         unsigned* __restrict__ gmaxU,
                                                         int M) {
    union LdsU {
        short a[64][K + 8];
        short ep[4][32][144];
    };
    __shared__ LdsU lds;

    int t = threadIdx.x;
    int w = t >> 6;
    int lane = t & 63;
    int quad = lane >> 4, l16 = lane & 15;
    int wm = w & 1, wn = w >> 1;
    int m0 = blockIdx.x * 64;
    int m_base = m0 + wm * 32;
    int n_base = wn * 128;

    // ---- stage A[64][K] in LDS, coalesced ----
    constexpr int SEGS = K / 8;
    constexpr int TOT = 64 * SEGS;
#pragma unroll
    for (int s = t; s < TOT; s += 256) {
        int row = s / SEGS;
        int ks = s % SEGS;
        int gr = m0 + row; if (gr >= M) gr = M - 1;
        *(short8*)&lds.a[row][ks * 8] = *(const short8*)&A[(size_t)gr * K + ks * 8];
    }
    __syncthreads();

    v4f acc[2][8] = {};

    for (int kt = 0; kt < K; kt += 32) {
        short8 a_frag[2];
#pragma unroll
        for (int mi = 0; mi < 2; mi++)
            a_frag[mi] = *(const short8*)&lds.a[wm * 32 + mi * 16 + l16][kt + quad * 8];
        short8 b_frag[8];
#pragma unroll
        for (int nj = 0; nj < 8; nj++) {
            int n = n_base + nj * 16 + l16;
            b_frag[nj] = *(const short8*)(Wt + (size_t)n * K + kt + quad * 8);
        }
#pragma unroll
        for (int mi = 0; mi < 2; mi++)
#pragma unroll
            for (int nj = 0; nj < 8; nj++)
                acc[mi][nj] = __builtin_amdgcn_mfma_f32_16x16x32_bf16(a_frag[mi], b_frag[nj],
                                                                      acc[mi][nj], 0, 0, 0);
    }
    __syncthreads();  // all waves done reading lds.a before ep overwrite

    // ---- stage output tile (bf16) in LDS ----
#pragma unroll
    for (int mi = 0; mi < 2; mi++)
#pragma unroll
        for (int r = 0; r < 4; r++) {
            int rl = mi * 16 + quad * 4 + r;
#pragma unroll
            for (int nj = 0; nj < 8; nj++)
                lds.ep[w][rl][nj * 16 + l16] = f2bf(acc[mi][nj][r]);
        }

    // ---- coalesced H write-out (same-wave LDS read, lgkmcnt handled by compiler) ----
    int rq = lane >> 4;
#pragma unroll
    for (int it = 0; it < 8; it++) {
        int rl = it * 4 + rq;
        int row = m_base + rl;
        if (row < M) {
            short8 v = *(const short8*)&lds.ep[w][rl][l16 * 8];
            *(short8*)&H[(size_t)row * HID + n_base + l16 * 8] = v;
        }
    }

    // ---- fused alpha: per (row, head) dots over this wave's tile ----
    // lane = r*2 + hp: r = lane>>1 (32 rows), hp = lane&1 (head pair)
    int r = lane >> 1;
    int hp = lane & 1;
    int node = m_base + r;
    int g0 = wn * 4 + hp * 2;          // global heads g0, g0+1
    const unsigned* p0 = (const unsigned*)&lds.ep[w][r][hp * 64];        // head g0: 32 ch
    const unsigned* p1 = p0 + 16;                                        // head g0+1
    const float4* as0 = (const float4*)(a_src + g0 * CH);
    const float4* ad0 = (const float4*)(a_dst + g0 * CH);
    const float4* as1 = (const float4*)(a_src + (g0 + 1) * CH);
    const float4* ad1 = (const float4*)(a_dst + (g0 + 1) * CH);
    float s0 = 0.f, s1 = 0.f, d0 = 0.f, d1 = 0.f;
#pragma unroll
    for (int c4 = 0; c4 < 8; c4++) {
        float4 a0 = as0[c4], b0 = ad0[c4], a1 = as1[c4], b1 = ad1[c4];
        unsigned u0 = p0[c4 * 2], u1 = p0[c4 * 2 + 1];
        unsigned v0 = p1[c4 * 2], v1 = p1[c4 * 2 + 1];
        s0 += bflo(u0) * a0.x + bfhi(u0) * a0.y + bflo(u1) * a0.z + bfhi(u1) * a0.w;
        d0 += bflo(u0) * b0.x + bfhi(u0) * b0.y + bflo(u1) * b0.z + bfhi(u1) * b0.w;
        s1 += bflo(v0) * a1.x + bfhi(v0) * a1.y + bflo(v1) * a1.z + bfhi(v1) * a1.w;
        d1 += bflo(v0) * b1.x + bfhi(v0) * b1.y + bflo(v1) * b1.z + bfhi(v1) * b1.w;
    }
    if (node < M) {
        *(float2*)&alS[node * HEADS + g0] = make_float2(s0, s1);
        *(float2*)&alD[node * HEADS + g0] = make_float2(d0, d1);
    }
    // per-head max across the wave's 32 rows (stride-2 lanes share head pair)
    float m0v = (node < M) ? s0 : -1e30f;
    float m1v = (node < M) ? s1 : -1e30f;
#pragma unroll
    for (int off = 2; off < 64; off <<= 1) {
        m0v = fmaxf(m0v, __shfl_xor(m0v, off));
        m1v = fmaxf(m1v, __shfl_xor(m1v, off));
    }
    if (r == 0) {
        atomicMax(&gmaxU[g0], fkey(m0v));
        atomicMax(&gmaxU[g0 + 1], fkey(m1v));
    }
}

// ---------------- fused attention: fixed-shift softmax, pure reduction loop ----------------

__global__ __launch_bounds__(256) void att_fused_kernel(const short* __restrict__ h,
                                                        const float* __restrict__ alS,
                                                        const float* __restrict__ alD,
                                                        const unsigned* __restrict__ gmaxU,
                                                        const int* __restrict__ row_ptr,
                                                        const int* __restrict__ srcs,
                                                        const float* __restrict__ bias,
                                                        short* __restrict__ out, int n) {
    int node = blockIdx.x * 4 + (threadIdx.x >> 6);
    if (node >= n) return;
    int lane = threadIdx.x & 63;
    int head = lane >> 3;
    int lo = row_ptr[node], hi = row_ptr[node + 1];
    float ald = alD[node * HEADS + head];
    float gm = unfkey(gmaxU[head]) + ald;
    float m = fmaxf(gm, NEG_SLOPE * gm);

    float denom = 0.f;
    float4 acc = make_float4(0.f, 0.f, 0.f, 0.f);

    int i = lo;
    for (; i + 4 <= hi; i += 4) {
        int s0 = srcs[i], s1 = srcs[i + 1], s2 = srcs[i + 2], s3 = srcs[i + 3];
        float x0 = alS[s0 * HEADS + head] + ald;
        float x1 = alS[s1 * HEADS + head] + ald;
        float x2 = alS[s2 * HEADS + head] + ald;
        float x3 = alS[s3 * HEADS + head] + ald;
        uint2 u0 = *(const uint2*)&h[(size_t)s0 * HID + lane * 4];
        uint2 u1 = *(const uint2*)&h[(size_t)s1 * HID + lane * 4];
        uint2 u2 = *(const uint2*)&h[(size_t)s2 * HID + lane * 4];
        uint2 u3 = *(const uint2*)&h[(size_t)s3 * HID + lane * 4];
        float w0 = __expf(fmaxf(x0, NEG_SLOPE * x0) - m);
        float w1 = __expf(fmaxf(x1, NEG_SLOPE * x1) - m);
        float w2 = __expf(fmaxf(x2, NEG_SLOPE * x2) - m);
        float w3 = __expf(fmaxf(x3, NEG_SLOPE * x3) - m);
        denom += (w0 + w1) + (w2 + w3);
        acc.x += w0 * bflo(u0.x) + w1 * bflo(u1.x) + w2 * bflo(u2.x) + w3 * bflo(u3.x);
        acc.y += w0 * bfhi(u0.x) + w1 * bfhi(u1.x) + w2 * bfhi(u2.x) + w3 * bfhi(u3.x);
        acc.z += w0 * bflo(u0.y) + w1 * bflo(u1.y) + w2 * bflo(u2.y) + w3 * bflo(u3.y);
        acc.w += w0 * bfhi(u0.y) + w1 * bfhi(u1.y) + w2 * bfhi(u2.y) + w3 * bfhi(u3.y);
    }
    for (; i < hi; i++) {
        int s0 = srcs[i];
        float x0 = alS[s0 * HEADS + head] + ald;
        float w0 = __expf(fmaxf(x0, NEG_SLOPE * x0) - m);
        uint2 u0 = *(const uint2*)&h[(size_t)s0 * HID + lane * 4];
        denom += w0;
        acc.x += w0 * bflo(u0.x);
        acc.y += w0 * bfhi(u0.x);
        acc.z += w0 * bflo(u0.y);
        acc.w += w0 * bfhi(u0.y);
    }
    float inv = 1.0f / (denom + 1e-16f);
    float4 b4 = *(const float4*)&bias[lane * 4];
    union { uint2 u; __hip_bfloat162 b[2]; } p;
    p.b[0] = __float22bfloat162_rn(make_float2(acc.x * inv + b4.x, acc.y * inv + b4.y));
    p.b[1] = __float22bfloat162_rn(make_float2(acc.z * inv + b4.z, acc.w * inv + b4.w));
    *(uint2*)&out[(size_t)node * HID + lane * 4] = p.u;
}

// ---------------- parallel mean pool (bf16 input) ----------------

#define POOL_CHUNK 64

__global__ __launch_bounds__(256) void pool_accum_kernel(const short* __restrict__ h,
                                                         const int* __restrict__ batch,
                                                         float* __restrict__ pooled,
                                                         int* __restrict__ cnt, int n) {
    int c0 = blockIdx.x * POOL_CHUNK;
    int c1 = c0 + POOL_CHUNK; if (c1 > n) c1 = n;
    int t = threadIdx.x;
    int g_cur = batch[c0];
    float acc = 0.f;
    int run = 0;
    for (int i = c0; i < c1; i++) {
        int g = batch[i];
        if (g != g_cur) {
            atomicAdd(&pooled[g_cur * HID + t], acc);
            if (t == 0) atomicAdd(&cnt[g_cur], run);
            acc = 0.f; run = 0; g_cur = g;
        }
        acc += bf2f(h[(size_t)i * HID + t]);
        run++;
    }
    atomicAdd(&pooled[g_cur * HID + t], acc);
    if (t == 0) atomicAdd(&cnt[g_cur], run);
}

// ---------------- final linear (with mean divide) ----------------

__global__ void final_kernel(const float* __restrict__ pooled, const int* __restrict__ cnt,
                             const float* __restrict__ W, const float* __restrict__ b,
                             float* __restrict__ out) {
    int idx = blockIdx.x * blockDim.x + threadIdx.x;
    if (idx >= NGRAPH * 10) return;
    int g = idx / 10, o = idx % 10;
    int c = cnt[g];
    float inv = 1.0f / (float)(c > 0 ? c : 1);
    float acc = b[o];
    for (int k = 0; k < HID; k++) acc += pooled[g * HID + k] * inv * W[k * 10 + o];
    out[idx] = acc;
}

extern "C" void kernel_launch(void* const* d_in, const int* in_sizes, int n_in,
                              void* d_out, int out_size, void* d_ws, size_t ws_size,
                              hipStream_t stream) {
    const float* x      = (const float*)d_in[0];
    const int*   ei     = (const int*)d_in[1];
    const int*   batch  = (const int*)d_in[2];
    const float* W0     = (const float*)d_in[3];
    const float* a_src0 = (const float*)d_in[4];
    const float* a_dst0 = (const float*)d_in[5];
    const float* b0     = (const float*)d_in[6];
    const float* Wh     = (const float*)d_in[7];   // [2,256,256]
    const float* a_srch = (const float*)d_in[8];   // [2,8,32]
    const float* a_dsth = (const float*)d_in[9];
    const float* bh     = (const float*)d_in[10];  // [2,256]
    const float* W_lin  = (const float*)d_in[11];
    const float* b_lin  = (const float*)d_in[12];
    float* out = (float*)d_out;

    // workspace carve-up
    short* hA     = (short*)d_ws;                    // 50000*256 bf16 (GEMM out)
    short* hB     = hA + (size_t)NN * HID;           // 50000*256 bf16 (att out)
    short* xb     = hB + (size_t)NN * HID;           // 50000*128 bf16
    short* Wt0    = xb + (size_t)NN * 128;           // 256*128
    short* Wt1    = Wt0 + 256 * 128;                 // 256*256
    short* Wt2    = Wt1 + 256 * 256;                 // 256*256
    float* alS    = (float*)(Wt2 + 256 * 256);
    float* alD    = alS + (size_t)NN * HEADS;
    float* pooled = alD + (size_t)NN * HEADS;        // 128*256
    int* cnt      = (int*)(pooled + NGRAPH * HID);   // 128
    unsigned* gmaxA = (unsigned*)(cnt + NGRAPH);     // 24 (3 layers x 8 heads)
    int* counts   = (int*)(gmaxA + 24);              // 50000
    int* row_ptr  = counts + NN;                     // 50001
    int* cursor   = row_ptr + NN + 1;                // 50000
    int* srcs     = cursor + NN;                     // 850000
    int* partial  = srcs + (NE + NN);                // 64
    int* blockOff = partial + 64;                    // 64

    const int NEP = NE + NN;
    const int NB_SCAN = (NN + 1023) / 1024;

    // CSR build
    init_counts_kernel<<<(NN + 255) / 256, 256, 0, stream>>>(counts, NN);
    count_edges_kernel<<<(NE + 255) / 256, 256, 0, stream>>>(ei + NE, counts, NE);
    scan_part_kernel<<<NB_SCAN, 1024, 0, stream>>>(counts, partial, NN);
    scan_offsets_kernel<<<1, 64, 0, stream>>>(partial, blockOff, NB_SCAN);
    scan_final_kernel<<<NB_SCAN, 1024, 0, stream>>>(counts, blockOff, row_ptr, cursor, NN);
    scatter_kernel<<<(NEP + 255) / 256, 256, 0, stream>>>(ei, cursor, srcs, NE, NN);

    // weight/x prep + zero-init (pooled + cnt + gmaxA contiguous)
    wcvt_kernel<<<256, 256, 0, stream>>>(W0, Wt0, 128);
    wcvt_kernel<<<256, 256, 0, stream>>>(Wh, Wt1, 256);
    wcvt_kernel<<<256, 256, 0, stream>>>(Wh + 256 * 256, Wt2, 256);
    xcvt_kernel<<<(NN * 128 / 4 + 255) / 256, 256, 0, stream>>>(x, xb, NN * 128 / 4);
    hipMemsetAsync(pooled, 0, (NGRAPH * HID + NGRAPH + 24) * sizeof(float), stream);

    const int gemm_grid = (NN + 63) / 64;
    const int agg_grid = (NN + 3) / 4;

    for (int l = 0; l < 3; l++) {
        const float* as = (l == 0) ? a_src0 : a_srch + (size_t)(l - 1) * HEADS * CH;
        const float* ad = (l == 0) ? a_dst0 : a_dsth + (size_t)(l - 1) * HEADS * CH;
        const float* bb = (l == 0) ? b0 : bh + (size_t)(l - 1) * HID;
        unsigned* gm = gmaxA + l * 8;

        if (l == 0)
            gemm_alpha_kernel<128><<<gemm_grid, 256, 0, stream>>>(xb, Wt0, as, ad, hA,
                                                                  alS, alD, gm, NN);
        else
            gemm_alpha_kernel<256><<<gemm_grid, 256, 0, stream>>>(hB, (l == 1) ? Wt1 : Wt2,
                                                                  as, ad, hA, alS, alD, gm, NN);
        att_fused_kernel<<<agg_grid, 256, 0, stream>>>(hA, alS, alD, gm, row_ptr, srcs, bb, hB, NN);
    }

    // pool + final linear
    pool_accum_kernel<<<(NN + POOL_CHUNK - 1) / POOL_CHUNK, 256, 0, stream>>>(hB, batch, pooled, cnt, NN);
    final_kernel<<<(NGRAPH * 10 + 255) / 256, 256, 0, stream>>>(pooled, cnt, W_lin, b_lin, out);
}

// Round 8
// 539.582 us; speedup vs baseline: 1.3341x; 1.3341x over previous
//
#include <hip/hip_runtime.h>
#include <hip/hip_bf16.h>
#include <math.h>

#define NN 50000
#define NE 800000
#define NGRAPH 128
#define HEADS 8
#define CH 32
#define HID 256
#define NEG_SLOPE 0.2f

typedef __attribute__((ext_vector_type(8))) short short8;
typedef __attribute__((ext_vector_type(4))) short short4v;
typedef __attribute__((ext_vector_type(4))) float v4f;

__device__ inline float bflo(unsigned u) { return __builtin_bit_cast(float, u << 16); }
__device__ inline float bfhi(unsigned u) { return __builtin_bit_cast(float, u & 0xFFFF0000u); }
__device__ inline float bf2f(short s) {
    return __builtin_bit_cast(float, ((unsigned)(unsigned short)s) << 16);
}
__device__ inline short f2bf(float f) {
    __hip_bfloat16 b = __float2bfloat16(f);
    return __builtin_bit_cast(short, b);
}

// ---------------- CSR build ----------------

__global__ void init_counts_kernel(int* counts, int n) {
    int i = blockIdx.x * blockDim.x + threadIdx.x;
    if (i < n) counts[i] = 1;  // self-loop
}

__global__ void count_edges_kernel(const int* __restrict__ dst, int* counts, int e) {
    int i = blockIdx.x * blockDim.x + threadIdx.x;
    if (i < e) atomicAdd(&counts[dst[i]], 1);
}

__device__ inline int wave_incl_scan(int v, int lane) {
#pragma unroll
    for (int off = 1; off < 64; off <<= 1) {
        int u = __shfl_up(v, off);
        if (lane >= off) v += u;
    }
    return v;
}

__global__ __launch_bounds__(1024) void scan_part_kernel(const int* __restrict__ counts,
                                                         int* partial, int n) {
    int i = blockIdx.x * 1024 + threadIdx.x;
    int v = (i < n) ? counts[i] : 0;
    int lane = threadIdx.x & 63, w = threadIdx.x >> 6;
    __shared__ int ws[16];
    int sv = wave_incl_scan(v, lane);
    if (lane == 63) ws[w] = sv;
    __syncthreads();
    if (threadIdx.x == 0) {
        int tot = 0;
#pragma unroll
        for (int j = 0; j < 16; j++) tot += ws[j];
        partial[blockIdx.x] = tot;
    }
}

__global__ void scan_offsets_kernel(const int* __restrict__ partial, int* blockOff, int nb) {
    int lane = threadIdx.x;
    int v = (lane < nb) ? partial[lane] : 0;
    int incl = wave_incl_scan(v, lane);
    if (lane < nb) blockOff[lane] = incl - v;
}

__global__ __launch_bounds__(1024) void scan_final_kernel(const int* __restrict__ counts,
                                                          const int* __restrict__ blockOff,
                                                          int* row_ptr, int* cursor, int n) {
    int i = blockIdx.x * 1024 + threadIdx.x;
    int v = (i < n) ? counts[i] : 0;
    int lane = threadIdx.x & 63, w = threadIdx.x >> 6;
    __shared__ int ws[17];
    int sv = wave_incl_scan(v, lane);
    if (lane == 63) ws[w] = sv;
    __syncthreads();
    if (w == 0) {
        int t = (lane < 16) ? ws[lane] : 0;
        int ts = wave_incl_scan(t, lane);
        if (lane < 16) ws[lane] = ts;
    }
    __syncthreads();
    int waveBase = (w > 0) ? ws[w - 1] : 0;
    int off = blockOff[blockIdx.x];
    int incl = waveBase + sv;
    if (i < n) {
        int ex = off + incl - v;
        row_ptr[i] = ex;
        cursor[i] = ex;
        if (i == n - 1) row_ptr[n] = off + incl;
    }
}

__global__ void scatter_kernel(const int* __restrict__ ei, int* cursor, int* srcs, int ne, int nn) {
    int i = blockIdx.x * blockDim.x + threadIdx.x;
    if (i < ne) {
        int s = ei[i];
        int d = ei[ne + i];
        int pos = atomicAdd(&cursor[d], 1);
        srcs[pos] = s;
    } else if (i < ne + nn) {
        int v = i - ne;
        int pos = atomicAdd(&cursor[v], 1);
        srcs[pos] = v;
    }
}

// ---------------- conversions ----------------

__global__ void xcvt_kernel(const float* __restrict__ x, short* __restrict__ xb, int n4) {
    int i = blockIdx.x * blockDim.x + threadIdx.x;
    if (i >= n4) return;
    float4 v = ((const float4*)x)[i];
    union { short4v s; __hip_bfloat162 b[2]; } p;
    p.b[0] = __float22bfloat162_rn(make_float2(v.x, v.y));
    p.b[1] = __float22bfloat162_rn(make_float2(v.z, v.w));
    ((short4v*)xb)[i] = p.s;
}

// W[K,256] f32 -> WtSwz bf16 in exact MFMA B-fragment consumption order:
// dst[((tile16*(K/32) + kc)*64 + quad*16 + l16)*8 + j] = W[kc*32+quad*8+j][tile16*16+l16]
__global__ void wcvt_swz_kernel(const float* __restrict__ W, short* __restrict__ Wt, int K) {
    int n = blockIdx.x;            // 0..255 output col
    int tile16 = n >> 4, l16 = n & 15;
    int KC = K >> 5;
    for (int k = threadIdx.x; k < K; k += blockDim.x) {
        int kc = k >> 5, quad = (k & 31) >> 3, j = k & 7;
        int lane = quad * 16 + l16;
        Wt[(size_t)(((tile16 * KC + kc) * 64 + lane)) * 8 + j] = f2bf(W[(size_t)k * 256 + n]);
    }
}

// ---------------- MFMA GEMM: H[M,256](bf16) = A[M,K](bf16) @ W (swizzled bf16) ----------------
// block = 64 rows x 256 cols, 4 waves, wave = 32 rows x 128 cols (2x8 mfma tiles)
// B loads fully coalesced via swizzled layout; LDS epilogue for coalesced bf16 stores

#define EP_STRIDE 144

template <int K>
__global__ __launch_bounds__(256) void gemm_mfma_kernel(const short* __restrict__ A,
                                                        const short* __restrict__ Wt,
                                                        short* __restrict__ H,
                                                        int M) {
    __shared__ short tile[4][32][EP_STRIDE];
    constexpr int KC = K >> 5;
    int w = threadIdx.x >> 6;
    int lane = threadIdx.x & 63;
    int quad = lane >> 4, l16 = lane & 15;
    int wm = w & 1, wn = w >> 1;
    int m_base = blockIdx.x * 64 + wm * 32;
    int n_base = wn * 128;

    v4f acc[2][8] = {};

    const short* aptr[2];
#pragma unroll
    for (int mi = 0; mi < 2; mi++) {
        int m = m_base + mi * 16 + l16;
        if (m >= M) m = M - 1;
        aptr[mi] = A + (size_t)m * K + quad * 8;
    }
    // swizzled B base for this wave: tiles wn*8 .. wn*8+7
    const short* bw = Wt + ((size_t)(wn * 8) * KC * 64 + lane) * 8;

#pragma unroll
    for (int kc = 0; kc < KC; kc++) {
        short8 a_frag[2];
#pragma unroll
        for (int mi = 0; mi < 2; mi++)
            a_frag[mi] = *(const short8*)(aptr[mi] + kc * 32);
        short8 b_frag[8];
#pragma unroll
        for (int nj = 0; nj < 8; nj++)
            b_frag[nj] = *(const short8*)(bw + (size_t)(nj * KC + kc) * 64 * 8);
#pragma unroll
        for (int mi = 0; mi < 2; mi++)
#pragma unroll
            for (int nj = 0; nj < 8; nj++)
                acc[mi][nj] = __builtin_amdgcn_mfma_f32_16x16x32_bf16(a_frag[mi], b_frag[nj],
                                                                      acc[mi][nj], 0, 0, 0);
    }

#pragma unroll
    for (int mi = 0; mi < 2; mi++)
#pragma unroll
        for (int r = 0; r < 4; r++) {
            int rl = mi * 16 + quad * 4 + r;
#pragma unroll
            for (int nj = 0; nj < 8; nj++)
                tile[w][rl][nj * 16 + l16] = f2bf(acc[mi][nj][r]);
        }
    __syncthreads();

    int rq = lane >> 4;
#pragma unroll
    for (int it = 0; it < 8; it++) {
        int rl = it * 4 + rq;
        int row = m_base + rl;
        if (row < M) {
            short8 v = *(const short8*)&tile[w][rl][l16 * 8];
            *(short8*)&H[(size_t)row * HID + n_base + l16 * 8] = v;
        }
    }
}

// ---------------- attention logits per node/head (reads bf16 h) ----------------

__global__ void alpha_kernel(const short* __restrict__ h, const float* __restrict__ a_src,
                             const float* __restrict__ a_dst, float* __restrict__ alS,
                             float* __restrict__ alD, int n) {
    int idx = blockIdx.x * blockDim.x + threadIdx.x;  // node*8 + head
    if (idx >= n * HEADS) return;
    int head = idx & 7;
    int node = idx >> 3;
    const unsigned* hp = (const unsigned*)(h + (size_t)node * HID + head * CH);
    const float* as = a_src + head * CH;
    const float* ad = a_dst + head * CH;
    float s1 = 0.f, s2 = 0.f;
#pragma unroll
    for (int c = 0; c < 16; c++) {
        unsigned u = hp[c];
        float v0 = bflo(u), v1 = bfhi(u);
        s1 += v0 * as[2 * c] + v1 * as[2 * c + 1];
        s2 += v0 * ad[2 * c] + v1 * ad[2 * c + 1];
    }
    alS[idx] = s1;
    alD[idx] = s2;
}

// ---------------- fused attention: 4-way-unrolled online softmax + weighted gather ----------------
// one wave per node; lane owns channels [lane*4, lane*4+4); head = lane>>3

__global__ __launch_bounds__(256) void att_fused_kernel(const short* __restrict__ h,
                                                        const float* __restrict__ alS,
                                                        const float* __restrict__ alD,
                                                        const int* __restrict__ row_ptr,
                                                        const int* __restrict__ srcs,
                                                        const float* __restrict__ bias,
                                                        short* __restrict__ out, int n) {
    int node = blockIdx.x * 4 + (threadIdx.x >> 6);
    if (node >= n) return;
    int lane = threadIdx.x & 63;
    int head = lane >> 3;
    int lo = row_ptr[node], hi = row_ptr[node + 1];
    float ald = alD[node * HEADS + head];

    float m = -1e30f;
    float denom = 0.f;
    float4 acc = make_float4(0.f, 0.f, 0.f, 0.f);

    int i = lo;
    for (; i + 4 <= hi; i += 4) {
        int s0 = srcs[i], s1 = srcs[i + 1], s2 = srcs[i + 2], s3 = srcs[i + 3];
        float x0 = alS[s0 * HEADS + head] + ald;
        float x1 = alS[s1 * HEADS + head] + ald;
        float x2 = alS[s2 * HEADS + head] + ald;
        float x3 = alS[s3 * HEADS + head] + ald;
        uint2 u0 = *(const uint2*)&h[(size_t)s0 * HID + lane * 4];
        uint2 u1 = *(const uint2*)&h[(size_t)s1 * HID + lane * 4];
        uint2 u2 = *(const uint2*)&h[(size_t)s2 * HID + lane * 4];
        uint2 u3 = *(const uint2*)&h[(size_t)s3 * HID + lane * 4];
        x0 = fmaxf(x0, NEG_SLOPE * x0);
        x1 = fmaxf(x1, NEG_SLOPE * x1);
        x2 = fmaxf(x2, NEG_SLOPE * x2);
        x3 = fmaxf(x3, NEG_SLOPE * x3);
        float mx = fmaxf(fmaxf(x0, x1), fmaxf(x2, x3));
        float mn = fmaxf(m, mx);
        float corr = __expf(m - mn);
        float w0 = __expf(x0 - mn);
        float w1 = __expf(x1 - mn);
        float w2 = __expf(x2 - mn);
        float w3 = __expf(x3 - mn);
        m = mn;
        denom = denom * corr + (w0 + w1) + (w2 + w3);
        acc.x = acc.x * corr + w0 * bflo(u0.x) + w1 * bflo(u1.x) + w2 * bflo(u2.x) + w3 * bflo(u3.x);
        acc.y = acc.y * corr + w0 * bfhi(u0.x) + w1 * bfhi(u1.x) + w2 * bfhi(u2.x) + w3 * bfhi(u3.x);
        acc.z = acc.z * corr + w0 * bflo(u0.y) + w1 * bflo(u1.y) + w2 * bflo(u2.y) + w3 * bflo(u3.y);
        acc.w = acc.w * corr + w0 * bfhi(u0.y) + w1 * bfhi(u1.y) + w2 * bfhi(u2.y) + w3 * bfhi(u3.y);
    }
    for (; i < hi; i++) {
        int s0 = srcs[i];
        float x0 = alS[s0 * HEADS + head] + ald;
        x0 = fmaxf(x0, NEG_SLOPE * x0);
        float mn = fmaxf(m, x0);
        float corr = __expf(m - mn);
        float w0 = __expf(x0 - mn);
        m = mn;
        uint2 u0 = *(const uint2*)&h[(size_t)s0 * HID + lane * 4];
        denom = denom * corr + w0;
        acc.x = acc.x * corr + w0 * bflo(u0.x);
        acc.y = acc.y * corr + w0 * bfhi(u0.x);
        acc.z = acc.z * corr + w0 * bflo(u0.y);
        acc.w = acc.w * corr + w0 * bfhi(u0.y);
    }
    float inv = 1.0f / (denom + 1e-16f);
    float4 b4 = *(const float4*)&bias[lane * 4];
    union { uint2 u; __hip_bfloat162 b[2]; } p;
    p.b[0] = __float22bfloat162_rn(make_float2(acc.x * inv + b4.x, acc.y * inv + b4.y));
    p.b[1] = __float22bfloat162_rn(make_float2(acc.z * inv + b4.z, acc.w * inv + b4.w));
    *(uint2*)&out[(size_t)node * HID + lane * 4] = p.u;
}

// ---------------- parallel mean pool (bf16 input) ----------------

#define POOL_CHUNK 64

__global__ __launch_bounds__(256) void pool_accum_kernel(const short* __restrict__ h,
                                                         const int* __restrict__ batch,
                                                         float* __restrict__ pooled,
                                                         int* __restrict__ cnt, int n) {
    int c0 = blockIdx.x * POOL_CHUNK;
    int c1 = c0 + POOL_CHUNK; if (c1 > n) c1 = n;
    int t = threadIdx.x;
    int g_cur = batch[c0];
    float acc = 0.f;
    int run = 0;
    for (int i = c0; i < c1; i++) {
        int g = batch[i];
        if (g != g_cur) {
            atomicAdd(&pooled[g_cur * HID + t], acc);
            if (t == 0) atomicAdd(&cnt[g_cur], run);
            acc = 0.f; run = 0; g_cur = g;
        }
        acc += bf2f(h[(size_t)i * HID + t]);
        run++;
    }
    atomicAdd(&pooled[g_cur * HID + t], acc);
    if (t == 0) atomicAdd(&cnt[g_cur], run);
}

// ---------------- final linear (with mean divide) ----------------

__global__ void final_kernel(const float* __restrict__ pooled, const int* __restrict__ cnt,
                             const float* __restrict__ W, const float* __restrict__ b,
                             float* __restrict__ out) {
    int idx = blockIdx.x * blockDim.x + threadIdx.x;
    if (idx >= NGRAPH * 10) return;
    int g = idx / 10, o = idx % 10;
    int c = cnt[g];
    float inv = 1.0f / (float)(c > 0 ? c : 1);
    float acc = b[o];
    for (int k = 0; k < HID; k++) acc += pooled[g * HID + k] * inv * W[k * 10 + o];
    out[idx] = acc;
}

extern "C" void kernel_launch(void* const* d_in, const int* in_sizes, int n_in,
                              void* d_out, int out_size, void* d_ws, size_t ws_size,
                              hipStream_t stream) {
    const float* x      = (const float*)d_in[0];
    const int*   ei     = (const int*)d_in[1];
    const int*   batch  = (const int*)d_in[2];
    const float* W0     = (const float*)d_in[3];
    const float* a_src0 = (const float*)d_in[4];
    const float* a_dst0 = (const float*)d_in[5];
    const float* b0     = (const float*)d_in[6];
    const float* Wh     = (const float*)d_in[7];   // [2,256,256]
    const float* a_srch = (const float*)d_in[8];   // [2,8,32]
    const float* a_dsth = (const float*)d_in[9];
    const float* bh     = (const float*)d_in[10];  // [2,256]
    const float* W_lin  = (const float*)d_in[11];
    const float* b_lin  = (const float*)d_in[12];
    float* out = (float*)d_out;

    // workspace carve-up
    short* hA     = (short*)d_ws;                    // 50000*256 bf16 (GEMM out)
    short* hB     = hA + (size_t)NN * HID;           // 50000*256 bf16 (att out)
    short* xb     = hB + (size_t)NN * HID;           // 50000*128 bf16
    short* Wt0    = xb + (size_t)NN * 128;           // 128*256 (swizzled)
    short* Wt1    = Wt0 + 256 * 128;                 // 256*256 (swizzled)
    short* Wt2    = Wt1 + 256 * 256;                 // 256*256 (swizzled)
    float* alS    = (float*)(Wt2 + 256 * 256);
    float* alD    = alS + (size_t)NN * HEADS;
    float* pooled = alD + (size_t)NN * HEADS;        // 128*256
    int* cnt      = (int*)(pooled + NGRAPH * HID);   // 128
    int* counts   = cnt + NGRAPH;                    // 50000
    int* row_ptr  = counts + NN;                     // 50001
    int* cursor   = row_ptr + NN + 1;                // 50000
    int* srcs     = cursor + NN;                     // 850000
    int* partial  = srcs + (NE + NN);                // 64
    int* blockOff = partial + 64;                    // 64

    const int NEP = NE + NN;
    const int NB_SCAN = (NN + 1023) / 1024;

    // CSR build
    init_counts_kernel<<<(NN + 255) / 256, 256, 0, stream>>>(counts, NN);
    count_edges_kernel<<<(NE + 255) / 256, 256, 0, stream>>>(ei + NE, counts, NE);
    scan_part_kernel<<<NB_SCAN, 1024, 0, stream>>>(counts, partial, NN);
    scan_offsets_kernel<<<1, 64, 0, stream>>>(partial, blockOff, NB_SCAN);
    scan_final_kernel<<<NB_SCAN, 1024, 0, stream>>>(counts, blockOff, row_ptr, cursor, NN);
    scatter_kernel<<<(NEP + 255) / 256, 256, 0, stream>>>(ei, cursor, srcs, NE, NN);

    // weight/x prep + zero-init
    wcvt_swz_kernel<<<256, 256, 0, stream>>>(W0, Wt0, 128);
    wcvt_swz_kernel<<<256, 256, 0, stream>>>(Wh, Wt1, 256);
    wcvt_swz_kernel<<<256, 256, 0, stream>>>(Wh + 256 * 256, Wt2, 256);
    xcvt_kernel<<<(NN * 128 / 4 + 255) / 256, 256, 0, stream>>>(x, xb, NN * 128 / 4);
    hipMemsetAsync(pooled, 0, (NGRAPH * HID + NGRAPH) * sizeof(float), stream);

    const int gemm_grid = (NN + 63) / 64;
    const int agg_grid = (NN + 3) / 4;

    for (int l = 0; l < 3; l++) {
        const float* as = (l == 0) ? a_src0 : a_srch + (size_t)(l - 1) * HEADS * CH;
        const float* ad = (l == 0) ? a_dst0 : a_dsth + (size_t)(l - 1) * HEADS * CH;
        const float* bb = (l == 0) ? b0 : bh + (size_t)(l - 1) * HID;

        if (l == 0)
            gemm_mfma_kernel<128><<<gemm_grid, 256, 0, stream>>>(xb, Wt0, hA, NN);
        else
            gemm_mfma_kernel<256><<<gemm_grid, 256, 0, stream>>>(hB, (l == 1) ? Wt1 : Wt2, hA, NN);
        alpha_kernel<<<(NN * HEADS + 255) / 256, 256, 0, stream>>>(hA, as, ad, alS, alD, NN);
        att_fused_kernel<<<agg_grid, 256, 0, stream>>>(hA, alS, alD, row_ptr, srcs, bb, hB, NN);
    }

    // pool + final linear
    pool_accum_kernel<<<(NN + POOL_CHUNK - 1) / POOL_CHUNK, 256, 0, stream>>>(hB, batch, pooled, cnt, NN);
    final_kernel<<<(NGRAPH * 10 + 255) / 256, 256, 0, stream>>>(pooled, cnt, W_lin, b_lin, out);
}

// Round 9
// 527.943 us; speedup vs baseline: 1.3635x; 1.0220x over previous
//
#include <hip/hip_runtime.h>
#include <hip/hip_bf16.h>
#include <math.h>

#define NN 50000
#define NE 800000
#define NGRAPH 128
#define HEADS 8
#define CH 32
#define HID 256
#define NEG_SLOPE 0.2f

typedef __attribute__((ext_vector_type(8))) short short8;
typedef __attribute__((ext_vector_type(4))) short short4v;
typedef __attribute__((ext_vector_type(4))) float v4f;

__device__ inline float bflo(unsigned u) { return __builtin_bit_cast(float, u << 16); }
__device__ inline float bfhi(unsigned u) { return __builtin_bit_cast(float, u & 0xFFFF0000u); }
__device__ inline float bf2f(short s) {
    return __builtin_bit_cast(float, ((unsigned)(unsigned short)s) << 16);
}
__device__ inline short f2bf(float f) {
    __hip_bfloat16 b = __float2bfloat16(f);
    return __builtin_bit_cast(short, b);
}
// monotonic float<->uint order-preserving map (for atomicMax on floats)
__device__ inline unsigned fkey(float f) {
    unsigned u = __builtin_bit_cast(unsigned, f);
    return (u & 0x80000000u) ? ~u : (u | 0x80000000u);
}
__device__ inline float unfkey(unsigned u) {
    unsigned v = (u & 0x80000000u) ? (u & 0x7FFFFFFFu) : ~u;
    return __builtin_bit_cast(float, v);
}

// ---------------- CSR build ----------------
// counts[] is pre-zeroed by memset; self-loop handled as +1 inside the scans.

__global__ void count_edges_kernel(const int* __restrict__ dst, int* counts, int e) {
    int i = blockIdx.x * blockDim.x + threadIdx.x;
    if (i < e) atomicAdd(&counts[dst[i]], 1);
}

__device__ inline int wave_incl_scan(int v, int lane) {
#pragma unroll
    for (int off = 1; off < 64; off <<= 1) {
        int u = __shfl_up(v, off);
        if (lane >= off) v += u;
    }
    return v;
}

__global__ __launch_bounds__(1024) void scan_part_kernel(const int* __restrict__ counts,
                                                         int* partial, int n) {
    int i = blockIdx.x * 1024 + threadIdx.x;
    int v = (i < n) ? counts[i] + 1 : 0;   // +1 self-loop
    int lane = threadIdx.x & 63, w = threadIdx.x >> 6;
    __shared__ int ws[16];
    int sv = wave_incl_scan(v, lane);
    if (lane == 63) ws[w] = sv;
    __syncthreads();
    if (threadIdx.x == 0) {
        int tot = 0;
#pragma unroll
        for (int j = 0; j < 16; j++) tot += ws[j];
        partial[blockIdx.x] = tot;
    }
}

__global__ void scan_offsets_kernel(const int* __restrict__ partial, int* blockOff, int nb) {
    int lane = threadIdx.x;
    int v = (lane < nb) ? partial[lane] : 0;
    int incl = wave_incl_scan(v, lane);
    if (lane < nb) blockOff[lane] = incl - v;
}

__global__ __launch_bounds__(1024) void scan_final_kernel(const int* __restrict__ counts,
                                                          const int* __restrict__ blockOff,
                                                          int* row_ptr, int* cursor, int n) {
    int i = blockIdx.x * 1024 + threadIdx.x;
    int v = (i < n) ? counts[i] + 1 : 0;   // +1 self-loop
    int lane = threadIdx.x & 63, w = threadIdx.x >> 6;
    __shared__ int ws[17];
    int sv = wave_incl_scan(v, lane);
    if (lane == 63) ws[w] = sv;
    __syncthreads();
    if (w == 0) {
        int t = (lane < 16) ? ws[lane] : 0;
        int ts = wave_incl_scan(t, lane);
        if (lane < 16) ws[lane] = ts;
    }
    __syncthreads();
    int waveBase = (w > 0) ? ws[w - 1] : 0;
    int off = blockOff[blockIdx.x];
    int incl = waveBase + sv;
    if (i < n) {
        int ex = off + incl - v;
        row_ptr[i] = ex;
        cursor[i] = ex;
        if (i == n - 1) row_ptr[n] = off + incl;
    }
}

__global__ void scatter_kernel(const int* __restrict__ ei, int* cursor, int* srcs, int ne, int nn) {
    int i = blockIdx.x * blockDim.x + threadIdx.x;
    if (i < ne) {
        int s = ei[i];
        int d = ei[ne + i];
        int pos = atomicAdd(&cursor[d], 1);
        srcs[pos] = s;
    } else if (i < ne + nn) {
        int v = i - ne;
        int pos = atomicAdd(&cursor[v], 1);
        srcs[pos] = v;
    }
}

// ---------------- conversions ----------------

__global__ void xcvt_kernel(const float* __restrict__ x, short* __restrict__ xb, int n4) {
    int i = blockIdx.x * blockDim.x + threadIdx.x;
    if (i >= n4) return;
    float4 v = ((const float4*)x)[i];
    union { short4v s; __hip_bfloat162 b[2]; } p;
    p.b[0] = __float22bfloat162_rn(make_float2(v.x, v.y));
    p.b[1] = __float22bfloat162_rn(make_float2(v.z, v.w));
    ((short4v*)xb)[i] = p.s;
}

// W[K,256] f32 -> WtSwz bf16 in exact MFMA B-fragment consumption order:
// dst[((tile16*(K/32) + kc)*64 + quad*16 + l16)*8 + j] = W[kc*32+quad*8+j][tile16*16+l16]
__global__ void wcvt_swz_kernel(const float* __restrict__ W, short* __restrict__ Wt, int K) {
    int n = blockIdx.x;            // 0..255 output col
    int tile16 = n >> 4, l16 = n & 15;
    int KC = K >> 5;
    for (int k = threadIdx.x; k < K; k += blockDim.x) {
        int kc = k >> 5, quad = (k & 31) >> 3, j = k & 7;
        int lane = quad * 16 + l16;
        Wt[(size_t)(((tile16 * KC + kc) * 64 + lane)) * 8 + j] = f2bf(W[(size_t)k * 256 + n]);
    }
}

// ---------------- MFMA GEMM: H[M,256](bf16) = A[M,K](bf16) @ W (swizzled bf16) ----------------
// block = 64 rows x 256 cols, 4 waves, wave = 32 rows x 128 cols (2x8 mfma tiles)
// B loads fully coalesced via swizzled layout; LDS epilogue for coalesced bf16 stores

#define EP_STRIDE 144

template <int K>
__global__ __launch_bounds__(256) void gemm_mfma_kernel(const short* __restrict__ A,
                                                        const short* __restrict__ Wt,
                                                        short* __restrict__ H,
                                                        int M) {
    __shared__ short tile[4][32][EP_STRIDE];
    constexpr int KC = K >> 5;
    int w = threadIdx.x >> 6;
    int lane = threadIdx.x & 63;
    int quad = lane >> 4, l16 = lane & 15;
    int wm = w & 1, wn = w >> 1;
    int m_base = blockIdx.x * 64 + wm * 32;
    int n_base = wn * 128;

    v4f acc[2][8] = {};

    const short* aptr[2];
#pragma unroll
    for (int mi = 0; mi < 2; mi++) {
        int m = m_base + mi * 16 + l16;
        if (m >= M) m = M - 1;
        aptr[mi] = A + (size_t)m * K + quad * 8;
    }
    // swizzled B base for this wave: tiles wn*8 .. wn*8+7
    const short* bw = Wt + ((size_t)(wn * 8) * KC * 64 + lane) * 8;

#pragma unroll
    for (int kc = 0; kc < KC; kc++) {
        short8 a_frag[2];
#pragma unroll
        for (int mi = 0; mi < 2; mi++)
            a_frag[mi] = *(const short8*)(aptr[mi] + kc * 32);
        short8 b_frag[8];
#pragma unroll
        for (int nj = 0; nj < 8; nj++)
            b_frag[nj] = *(const short8*)(bw + (size_t)(nj * KC + kc) * 64 * 8);
#pragma unroll
        for (int mi = 0; mi < 2; mi++)
#pragma unroll
            for (int nj = 0; nj < 8; nj++)
                acc[mi][nj] = __builtin_amdgcn_mfma_f32_16x16x32_bf16(a_frag[mi], b_frag[nj],
                                                                      acc[mi][nj], 0, 0, 0);
    }

#pragma unroll
    for (int mi = 0; mi < 2; mi++)
#pragma unroll
        for (int r = 0; r < 4; r++) {
            int rl = mi * 16 + quad * 4 + r;
#pragma unroll
            for (int nj = 0; nj < 8; nj++)
                tile[w][rl][nj * 16 + l16] = f2bf(acc[mi][nj][r]);
        }
    __syncthreads();

    int rq = lane >> 4;
#pragma unroll
    for (int it = 0; it < 8; it++) {
        int rl = it * 4 + rq;
        int row = m_base + rl;
        if (row < M) {
            short8 v = *(const short8*)&tile[w][rl][l16 * 8];
            *(short8*)&H[(size_t)row * HID + n_base + l16 * 8] = v;
        }
    }
}

// ---------------- attention logits per node/head + fused per-head global max ----------------
// grid-strided (stride multiple of 8 keeps head = tid&7 invariant)

__global__ __launch_bounds__(256) void alpha_kernel(const short* __restrict__ h,
                                                    const float* __restrict__ a_src,
                                                    const float* __restrict__ a_dst,
                                                    float* __restrict__ alS,
                                                    float* __restrict__ alD,
                                                    unsigned* __restrict__ gmaxU, int n) {
    __shared__ unsigned sm[HEADS];
    int t = threadIdx.x;
    if (t < HEADS) sm[t] = 0u;
    __syncthreads();
    int head = t & 7;
    const float* as = a_src + head * CH;
    const float* ad = a_dst + head * CH;
    unsigned lmax = 0u;
    for (int idx = blockIdx.x * 256 + t; idx < n * HEADS; idx += gridDim.x * 256) {
        int node = idx >> 3;
        const unsigned* hp = (const unsigned*)(h + (size_t)node * HID + head * CH);
        float s1 = 0.f, s2 = 0.f;
#pragma unroll
        for (int c = 0; c < 16; c++) {
            unsigned u = hp[c];
            float v0 = bflo(u), v1 = bfhi(u);
            s1 += v0 * as[2 * c] + v1 * as[2 * c + 1];
            s2 += v0 * ad[2 * c] + v1 * ad[2 * c + 1];
        }
        alS[idx] = s1;
        alD[idx] = s2;
        lmax = max(lmax, fkey(s1));
    }
    atomicMax(&sm[head], lmax);
    __syncthreads();
    if (t < HEADS) atomicMax(&gmaxU[t], sm[t]);
}

// ---------------- fused attention: fixed-shift softmax, lane-parallel weights ----------------
// one wave per node; lane = head*8+sub owns channels [lane*4, lane*4+4)
// per 8-edge group: lane sub computes exp for edge i+sub; bpermute broadcasts w;
// readlane scalarizes src -> sgpr-base h gather.

__global__ __launch_bounds__(256) void att_fused_kernel(const short* __restrict__ h,
                                                        const float* __restrict__ alS,
                                                        const float* __restrict__ alD,
                                                        const unsigned* __restrict__ gmaxU,
                                                        const int* __restrict__ row_ptr,
                                                        const int* __restrict__ srcs,
                                                        const float* __restrict__ bias,
                                                        short* __restrict__ out, int n) {
    int node = blockIdx.x * 4 + (threadIdx.x >> 6);
    if (node >= n) return;
    int lane = threadIdx.x & 63;
    int head = lane >> 3, sub = lane & 7;
    int lo = row_ptr[node], hi = row_ptr[node + 1];
    float ald = alD[node * HEADS + head];
    // safe fixed shift: leaky monotonic => leaky(gmax + ald) >= all edge logits of this node/head
    float gm = unfkey(gmaxU[head]) + ald;
    float m = fmaxf(gm, NEG_SLOPE * gm);
    int vbase = (lane & 56) << 2;   // bpermute byte-addr base of this head group
    int choff = lane * 4;           // channel offset (shorts)

    float denom = 0.f;
    float4 acc = make_float4(0.f, 0.f, 0.f, 0.f);

    int i = lo;
    for (; i + 8 <= hi; i += 8) {
        int sj = srcs[i + sub];
        float x = alS[sj * HEADS + head] + ald;
        x = fmaxf(x, NEG_SLOPE * x);
        float wgt = __expf(x - m);
        denom += wgt;
        int wb = __builtin_bit_cast(int, wgt);
#pragma unroll
        for (int jj = 0; jj < 8; jj++) {
            float wj = __builtin_bit_cast(float,
                        __builtin_amdgcn_ds_bpermute(vbase + jj * 4, wb));
            int s = __builtin_amdgcn_readlane(sj, jj);   // uniform: srcs[i+jj]
            uint2 u = *(const uint2*)&h[(size_t)s * HID + choff];
            acc.x += wj * bflo(u.x);
            acc.y += wj * bfhi(u.x);
            acc.z += wj * bflo(u.y);
            acc.w += wj * bfhi(u.y);
        }
    }
    if (i < hi) {
        int rem = hi - i;
        int sj = srcs[i + (sub < rem ? sub : 0)];
        float x = alS[sj * HEADS + head] + ald;
        x = fmaxf(x, NEG_SLOPE * x);
        float we = __expf(x - m);
        float wgt = (sub < rem) ? we : 0.f;
        denom += wgt;
        int wb = __builtin_bit_cast(int, wgt);
        for (int jj = 0; jj < rem; jj++) {
            float wj = __builtin_bit_cast(float,
                        __builtin_amdgcn_ds_bpermute(vbase + jj * 4, wb));
            int s = __builtin_amdgcn_readlane(sj, jj);
            uint2 u = *(const uint2*)&h[(size_t)s * HID + choff];
            acc.x += wj * bflo(u.x);
            acc.y += wj * bfhi(u.x);
            acc.z += wj * bflo(u.y);
            acc.w += wj * bfhi(u.y);
        }
    }
    // head-group denom reduction (8 lanes)
    denom += __shfl_xor(denom, 1);
    denom += __shfl_xor(denom, 2);
    denom += __shfl_xor(denom, 4);

    float inv = 1.0f / (denom + 1e-16f);
    float4 b4 = *(const float4*)&bias[choff];
    union { uint2 u; __hip_bfloat162 b[2]; } p;
    p.b[0] = __float22bfloat162_rn(make_float2(acc.x * inv + b4.x, acc.y * inv + b4.y));
    p.b[1] = __float22bfloat162_rn(make_float2(acc.z * inv + b4.z, acc.w * inv + b4.w));
    *(uint2*)&out[(size_t)node * HID + choff] = p.u;
}

// ---------------- parallel mean pool (bf16 input) ----------------

#define POOL_CHUNK 64

__global__ __launch_bounds__(256) void pool_accum_kernel(const short* __restrict__ h,
                                                         const int* __restrict__ batch,
                                                         float* __restrict__ pooled,
                                                         int* __restrict__ cnt, int n) {
    int c0 = blockIdx.x * POOL_CHUNK;
    int c1 = c0 + POOL_CHUNK; if (c1 > n) c1 = n;
    int t = threadIdx.x;
    int g_cur = batch[c0];
    float acc = 0.f;
    int run = 0;
    for (int i = c0; i < c1; i++) {
        int g = batch[i];
        if (g != g_cur) {
            atomicAdd(&pooled[g_cur * HID + t], acc);
            if (t == 0) atomicAdd(&cnt[g_cur], run);
            acc = 0.f; run = 0; g_cur = g;
        }
        acc += bf2f(h[(size_t)i * HID + t]);
        run++;
    }
    atomicAdd(&pooled[g_cur * HID + t], acc);
    if (t == 0) atomicAdd(&cnt[g_cur], run);
}

// ---------------- final linear (with mean divide) ----------------

__global__ void final_kernel(const float* __restrict__ pooled, const int* __restrict__ cnt,
                             const float* __restrict__ W, const float* __restrict__ b,
                             float* __restrict__ out) {
    int idx = blockIdx.x * blockDim.x + threadIdx.x;
    if (idx >= NGRAPH * 10) return;
    int g = idx / 10, o = idx % 10;
    int c = cnt[g];
    float inv = 1.0f / (float)(c > 0 ? c : 1);
    float acc = b[o];
    for (int k = 0; k < HID; k++) acc += pooled[g * HID + k] * inv * W[k * 10 + o];
    out[idx] = acc;
}

extern "C" void kernel_launch(void* const* d_in, const int* in_sizes, int n_in,
                              void* d_out, int out_size, void* d_ws, size_t ws_size,
                              hipStream_t stream) {
    const float* x      = (const float*)d_in[0];
    const int*   ei     = (const int*)d_in[1];
    const int*   batch  = (const int*)d_in[2];
    const float* W0     = (const float*)d_in[3];
    const float* a_src0 = (const float*)d_in[4];
    const float* a_dst0 = (const float*)d_in[5];
    const float* b0     = (const float*)d_in[6];
    const float* Wh     = (const float*)d_in[7];   // [2,256,256]
    const float* a_srch = (const float*)d_in[8];   // [2,8,32]
    const float* a_dsth = (const float*)d_in[9];
    const float* bh     = (const float*)d_in[10];  // [2,256]
    const float* W_lin  = (const float*)d_in[11];
    const float* b_lin  = (const float*)d_in[12];
    float* out = (float*)d_out;

    // workspace carve-up (pooled..counts contiguous for single memset)
    short* hA     = (short*)d_ws;                    // 50000*256 bf16 (GEMM out)
    short* hB     = hA + (size_t)NN * HID;           // 50000*256 bf16 (att out)
    short* xb     = hB + (size_t)NN * HID;           // 50000*128 bf16
    short* Wt0    = xb + (size_t)NN * 128;           // 128*256 (swizzled)
    short* Wt1    = Wt0 + 256 * 128;                 // 256*256 (swizzled)
    short* Wt2    = Wt1 + 256 * 256;                 // 256*256 (swizzled)
    float* alS    = (float*)(Wt2 + 256 * 256);
    float* alD    = alS + (size_t)NN * HEADS;
    float* pooled = alD + (size_t)NN * HEADS;        // 128*256
    int* cnt      = (int*)(pooled + NGRAPH * HID);   // 128
    unsigned* gmaxA = (unsigned*)(cnt + NGRAPH);     // 24 (3 layers x 8 heads)
    int* counts   = (int*)(gmaxA + 24);              // 50000
    int* row_ptr  = counts + NN;                     // 50001
    int* cursor   = row_ptr + NN + 1;                // 50000
    int* srcs     = cursor + NN;                     // 850000
    int* partial  = srcs + (NE + NN);                // 64
    int* blockOff = partial + 64;                    // 64

    const int NEP = NE + NN;
    const int NB_SCAN = (NN + 1023) / 1024;

    // single zero-init: pooled + cnt + gmaxA + counts
    hipMemsetAsync(pooled, 0, (NGRAPH * HID + NGRAPH + 24 + NN) * sizeof(float), stream);

    // CSR build
    count_edges_kernel<<<(NE + 255) / 256, 256, 0, stream>>>(ei + NE, counts, NE);
    scan_part_kernel<<<NB_SCAN, 1024, 0, stream>>>(counts, partial, NN);
    scan_offsets_kernel<<<1, 64, 0, stream>>>(partial, blockOff, NB_SCAN);
    scan_final_kernel<<<NB_SCAN, 1024, 0, stream>>>(counts, blockOff, row_ptr, cursor, NN);
    scatter_kernel<<<(NEP + 255) / 256, 256, 0, stream>>>(ei, cursor, srcs, NE, NN);

    // weight/x prep
    wcvt_swz_kernel<<<256, 256, 0, stream>>>(W0, Wt0, 128);
    wcvt_swz_kernel<<<256, 256, 0, stream>>>(Wh, Wt1, 256);
    wcvt_swz_kernel<<<256, 256, 0, stream>>>(Wh + 256 * 256, Wt2, 256);
    xcvt_kernel<<<(NN * 128 / 4 + 255) / 256, 256, 0, stream>>>(x, xb, NN * 128 / 4);

    const int gemm_grid = (NN + 63) / 64;
    const int agg_grid = (NN + 3) / 4;

    for (int l = 0; l < 3; l++) {
        const float* as = (l == 0) ? a_src0 : a_srch + (size_t)(l - 1) * HEADS * CH;
        const float* ad = (l == 0) ? a_dst0 : a_dsth + (size_t)(l - 1) * HEADS * CH;
        const float* bb = (l == 0) ? b0 : bh + (size_t)(l - 1) * HID;
        unsigned* gm = gmaxA + l * 8;

        if (l == 0)
            gemm_mfma_kernel<128><<<gemm_grid, 256, 0, stream>>>(xb, Wt0, hA, NN);
        else
            gemm_mfma_kernel<256><<<gemm_grid, 256, 0, stream>>>(hB, (l == 1) ? Wt1 : Wt2, hA, NN);
        alpha_kernel<<<512, 256, 0, stream>>>(hA, as, ad, alS, alD, gm, NN);
        att_fused_kernel<<<agg_grid, 256, 0, stream>>>(hA, alS, alD, gm, row_ptr, srcs, bb, hB, NN);
    }

    // pool + final linear
    pool_accum_kernel<<<(NN + POOL_CHUNK - 1) / POOL_CHUNK, 256, 0, stream>>>(hB, batch, pooled, cnt, NN);
    final_kernel<<<(NGRAPH * 10 + 255) / 256, 256, 0, stream>>>(pooled, cnt, W_lin, b_lin, out);
}